// Round 8
// baseline (209.962 us; speedup 1.0000x reference)
//
#include <hip/hip_runtime.h>
#include <math.h>

// ViT Vector Quantizer: z [32,1024,32] f32, embedding [8192,32] f32.
// Outputs (concat, read as f32): z_q_out [N*D], loss [1], idx [N] (as floats).
//
// R8: pipelined split-bf16 MFMA argmin + parallel exact-rescore.
//   K0 k_prep        : codebook only: normalize -> en, en_h, bf16 hi/lo B-frag
//                      swizzle (eswz); cnt=loss=0.  (z swizzle ELIMINATED --
//                      argmin lanes build their own A-fragments.)
//   K1 k_argmin_mfma : per tile: 2 independent MFMA chains (hh | hl->lh) + reg-
//                      pipelined B-fragment prefetch (R7 exposed ~120cyc ds_read
//                      + 3-chain MFMA latency serially per tile -> 222 cyc/tile).
//                      Scores offset +1.25 (positive) -> packed u32 top-2 via
//                      and_or/min/max; flag if quantized gap < 5e-4.
//   K2 k_cleanup     : flagged rows exact fp32 rescore, thread-per-code.
//   K3 k_epi         : decode sentinel, gather en[idx], write outputs.

#define D 32
#define KCODES 8192
#define MARGIN_Q 5.0e-4f   // split-bf16 err (~2.4e-5) + u32 9-bit quant step (2.44e-4), inflated
#define EPS 1e-12f

typedef short bf16x8 __attribute__((ext_vector_type(8)));
typedef unsigned short u16x8 __attribute__((ext_vector_type(8)));
typedef float f32x4 __attribute__((ext_vector_type(4)));

static __device__ __forceinline__ unsigned short f2bf(float x) {  // RNE bf16 bits
  unsigned u = __float_as_uint(x);
  return (unsigned short)((u + 0x7FFFu + ((u >> 16) & 1u)) >> 16);
}
static __device__ __forceinline__ float bf2f(unsigned short s) {
  return __uint_as_float(((unsigned)s) << 16);
}
static __device__ __forceinline__ void gload_lds16(const void* g, void* l) {
  __builtin_amdgcn_global_load_lds(
      (const __attribute__((address_space(1))) void*)g,
      (__attribute__((address_space(3))) void*)l, 16, 0, 0);
}

// MFMA fragment layouts (validated by R5-R7 exact-idx passes):
//   A[m][k]: m = lane&15, k = (lane>>4)*8 + j
//   B[k][n]: n = lane&15, k = (lane>>4)*8 + j
//   C[m][n]: n = lane&15, m = (lane>>4)*4 + reg

__global__ __launch_bounds__(256) void k_prep(const float* __restrict__ emb,
                                              float* __restrict__ en,
                                              float* __restrict__ en_h,
                                              unsigned short* __restrict__ eswz,
                                              int* __restrict__ cnt,
                                              float* __restrict__ loss) {
  int v = blockIdx.x * 256 + threadIdx.x;
  if (v == 0) { *cnt = 0; *loss = 0.f; }
  if (v >= KCODES) return;

  float x[D];
  const float4* p = reinterpret_cast<const float4*>(emb + (size_t)v * D);
#pragma unroll
  for (int j = 0; j < D / 4; ++j) {
    float4 q = p[j];
    x[4 * j + 0] = q.x; x[4 * j + 1] = q.y; x[4 * j + 2] = q.z; x[4 * j + 3] = q.w;
  }
  float ss = 0.f;
#pragma unroll
  for (int j = 0; j < D; ++j) ss = fmaf(x[j], x[j], ss);
  float n = fmaxf(sqrtf(ss), EPS);
#pragma unroll
  for (int j = 0; j < D; ++j) x[j] = x[j] / n;   // true division mirrors reference

  float4* o = reinterpret_cast<float4*>(en + (size_t)v * D);
  float s2 = 0.f;
#pragma unroll
  for (int j = 0; j < D / 4; ++j) {
    float4 q = {x[4 * j], x[4 * j + 1], x[4 * j + 2], x[4 * j + 3]};
    s2 = fmaf(q.x, q.x, fmaf(q.y, q.y, fmaf(q.z, q.z, fmaf(q.w, q.w, s2))));
    o[j] = q;
  }
  en_h[v] = 0.5f * s2;

  unsigned short hi[D], lo[D];
#pragma unroll
  for (int j = 0; j < D; ++j) {
    hi[j] = f2bf(x[j]);
    lo[j] = f2bf(x[j] - bf2f(hi[j]));   // x - bf16(x) exact in fp32
  }
  int tl = v >> 4, m = v & 15;          // B-fragment swizzle: tile = 1024 shorts
#pragma unroll
  for (int q = 0; q < 4; ++q) {
    u16x8 hv, lv;
#pragma unroll
    for (int j = 0; j < 8; ++j) { hv[j] = hi[8 * q + j]; lv[j] = lo[8 * q + j]; }
    *(u16x8*)(eswz + (size_t)tl * 1024 + (q * 16 + m) * 8) = hv;
    *(u16x8*)(eswz + (size_t)tl * 1024 + 512 + (q * 16 + m) * 8) = lv;
  }
}

// 256 thr = 4 waves (one 16-row group each); 512 blocks = 2/CU.
__global__ __launch_bounds__(256, 2) void k_argmin_mfma(
    const float* __restrict__ z,
    const unsigned short* __restrict__ eswz,
    int* __restrict__ idx_ws, int* __restrict__ list, int* __restrict__ cnt,
    unsigned long long* __restrict__ mp2) {
  __shared__ unsigned short lds_sh[2][16384];   // 2 x 32 KB double buffer

  const int tid = threadIdx.x;
  const int wid = tid >> 6, lane = tid & 63;
  const int lane15 = lane & 15, quad = lane >> 4;
  const int g = blockIdx.x * 4 + wid;           // 16-row group per wave

  // issue chunk-0 DMA first so it overlaps the z prologue
  const float4* gall = reinterpret_cast<const float4*>(eswz);
#pragma unroll
  for (int i = 0; i < 8; ++i) {
    int off = i * 256 + tid;                    // wave-uniform base + lane*16B
    gload_lds16(gall + off, (char*)&lds_sh[0][0] + (size_t)off * 16);
  }

  // --- A-fragment built in-place: row = g*16+lane15, dims quad*8..quad*8+7.
  // 4 lanes share a row (redundant 4x, L2-served); norm order matches reference.
  bf16x8 zhi, zlo;
  {
    const float4* p = reinterpret_cast<const float4*>(z + (size_t)(g * 16 + lane15) * D);
    float ss = 0.f;
#pragma unroll
    for (int j = 0; j < 8; ++j) {
      float4 q = p[j];
      ss = fmaf(q.x, q.x, fmaf(q.y, q.y, fmaf(q.z, q.z, fmaf(q.w, q.w, ss))));
    }
    float nn = fmaxf(sqrtf(ss), EPS);
    float4 a0 = p[quad * 2], a1 = p[quad * 2 + 1];   // this lane's 8 dims (addr-dynamic, reg-static)
    float xs[8] = {a0.x / nn, a0.y / nn, a0.z / nn, a0.w / nn,
                   a1.x / nn, a1.y / nn, a1.z / nn, a1.w / nn};
#pragma unroll
    for (int j = 0; j < 8; ++j) {
      unsigned short h = f2bf(xs[j]);
      zhi[j] = (short)h;
      zlo[j] = (short)f2bf(xs[j] - bf2f(h));
    }
  }

  unsigned p1[4], p2[4];
#pragma unroll
  for (int r = 0; r < 4; ++r) { p1[r] = 0u; p2[r] = 0u; }
  const f32x4 initA = {1.25f, 1.25f, 1.25f, 1.25f};  // score offset: s' = 1.25+dot > 0
  const f32x4 zero4 = {0.f, 0.f, 0.f, 0.f};

  for (int c = 0; c < 32; ++c) {
    __syncthreads();              // buffer c&1 fully staged
    if (c + 1 < 32) {             // next DMA overlaps this chunk's compute
      const float4* gn = gall + (size_t)(c + 1) * 2048;
      char* dst = (char*)&lds_sh[(c + 1) & 1][0];
#pragma unroll
      for (int i = 0; i < 8; ++i) {
        int off = i * 256 + tid;
        gload_lds16(gn + off, dst + (size_t)off * 16);
      }
    }
    const unsigned short* buf = &lds_sh[c & 1][0];
    bf16x8 cbh = *(const bf16x8*)(buf + lane * 8);          // tile 0
    bf16x8 cbl = *(const bf16x8*)(buf + 512 + lane * 8);
    const unsigned tbase = (unsigned)(511 - c * 16);
#pragma unroll
    for (int t = 0; t < 16; ++t) {
      bf16x8 nbh, nbl;
      if (t < 15) {               // register-pipelined prefetch of tile t+1
        nbh = *(const bf16x8*)(buf + (t + 1) * 1024 + lane * 8);
        nbl = *(const bf16x8*)(buf + (t + 1) * 1024 + 512 + lane * 8);
      }
      // two INDEPENDENT MFMA chains: hh | (hl -> lh)
      f32x4 aa = __builtin_amdgcn_mfma_f32_16x16x32_bf16(zhi, cbh, initA, 0, 0, 0);
      f32x4 ab = __builtin_amdgcn_mfma_f32_16x16x32_bf16(zhi, cbl, zero4, 0, 0, 0);
      ab = __builtin_amdgcn_mfma_f32_16x16x32_bf16(zlo, cbh, ab, 0, 0, 0);
      const unsigned tid9 = tbase - t;          // 511 - tile_global (tie -> min k)
#pragma unroll
      for (int r = 0; r < 4; ++r) {
        float sa = aa[r] + ab[r];               // positive -> bits order as uint
        unsigned pk = (__float_as_uint(sa) & 0xFFFFFE00u) | tid9;  // v_and_or_b32
        unsigned tmin = (pk < p1[r]) ? pk : p1[r];
        p1[r] = (pk > p1[r]) ? pk : p1[r];
        p2[r] = (tmin > p2[r]) ? tmin : p2[r];
      }
      cbh = nbh; cbl = nbl;
    }
  }

  // cross-lane merge over the 16 lanes of this quad (rows quad*4 .. quad*4+3)
#pragma unroll
  for (int r = 0; r < 4; ++r) {
    int kl = (511 - (int)(p1[r] & 511u)) * 16 + lane15;
    unsigned sb = p1[r] & 0xFFFFFE00u;
    float s1f = __uint_as_float(sb);
    float s2f = __uint_as_float(p2[r] & 0xFFFFFE00u);
    unsigned long long pk =
        ((unsigned long long)sb << 32) | (unsigned)(8191 - kl);
#pragma unroll
    for (int m = 1; m <= 8; m <<= 1) {
      unsigned long long op = __shfl_xor(pk, m, 64);
      float os1 = __shfl_xor(s1f, m, 64);
      float os2 = __shfl_xor(s2f, m, 64);
      s2f = fmaxf(fmaxf(s2f, os2), fminf(s1f, os1));  // union 2nd-best
      s1f = fmaxf(s1f, os1);
      pk = (op > pk) ? op : pk;                       // max s, tie -> min k
    }
    if (lane15 == 0) {
      int orow = g * 16 + quad * 4 + r;
      if (s1f - s2f < MARGIN_Q) {            // ambiguous -> exact rescore
        int pos = atomicAdd(cnt, 1);
        list[pos] = orow;
        mp2[pos] = 0ull;                     // atomicMax identity
        idx_ws[orow] = -(pos + 1);           // sentinel, resolved in epi
      } else {
        idx_ws[orow] = 8191 - (int)(unsigned)(pk & 0xFFFFFFFFull);
      }
    }
  }
}

// Exact fp32 rescore, thread-per-code; block-reduce + one atomicMax per block.
__global__ __launch_bounds__(256) void k_cleanup(const float* __restrict__ z,
                                                 const float* __restrict__ en,
                                                 const float* __restrict__ en_h,
                                                 const int* __restrict__ list,
                                                 const int* __restrict__ cnt,
                                                 unsigned long long* __restrict__ mp2) {
  __shared__ unsigned long long wred[4];
  const int tid = threadIdx.x;
  const int lane = tid & 63, wid = tid >> 6;
  const int ntask = (*cnt) * 32;               // 32 chunks of 256 codes per row

  for (int j = blockIdx.x; j < ntask; j += gridDim.x) {
    int i = j >> 5, kc = j & 31;
    int row = list[i];
    const float* zr = z + (size_t)row * D;     // wave-uniform -> scalar loads
    float v[D];
    float ss = 0.f;
#pragma unroll
    for (int d = 0; d < D; ++d) v[d] = zr[d];
#pragma unroll
    for (int d = 0; d < D; ++d) ss = fmaf(v[d], v[d], ss);
    float n = fmaxf(sqrtf(ss), EPS);
#pragma unroll
    for (int d = 0; d < D; ++d) v[d] = v[d] / n;

    int k = kc * 256 + tid;                    // contiguous -> coalesced
    const float4* er = reinterpret_cast<const float4*>(en + (size_t)k * D);
    float a = -en_h[k];
#pragma unroll
    for (int jj = 0; jj < 8; ++jj) {           // exact R4 fma order
      float4 e = er[jj];
      a = fmaf(v[4 * jj + 0], e.x, a);
      a = fmaf(v[4 * jj + 1], e.y, a);
      a = fmaf(v[4 * jj + 2], e.z, a);
      a = fmaf(v[4 * jj + 3], e.w, a);
    }
    unsigned o = __float_as_uint(a);
    o = (o & 0x80000000u) ? ~o : (o | 0x80000000u);
    unsigned long long pk = ((unsigned long long)o << 32) | (unsigned)(8191 - k);
#pragma unroll
    for (int m = 32; m >= 1; m >>= 1) {
      unsigned long long op = __shfl_xor(pk, m, 64);
      pk = (op > pk) ? op : pk;                // max s, tie -> min k
    }
    if (lane == 0) wred[wid] = pk;
    __syncthreads();
    if (tid == 0) {
      unsigned long long m01 = (wred[0] > wred[1]) ? wred[0] : wred[1];
      unsigned long long m23 = (wred[2] > wred[3]) ? wred[2] : wred[3];
      atomicMax(&mp2[i], (m01 > m23) ? m01 : m23);
    }
    __syncthreads();                           // protect wred for next task
  }
}

__global__ __launch_bounds__(256) void k_epi(const float* __restrict__ z,
                                             const float* __restrict__ en,
                                             const int* __restrict__ idx_ws,
                                             const unsigned long long* __restrict__ mp2,
                                             float* __restrict__ out_z,
                                             float* __restrict__ loss,
                                             float* __restrict__ out_idx,
                                             float scale) {
  int row = blockIdx.x * 256 + threadIdx.x;
  int kb = idx_ws[row];
  if (kb < 0) {                                // flagged: exact result in mp2
    unsigned long long m = mp2[-kb - 1];
    kb = 8191 - (int)(unsigned)(m & 0xFFFFFFFFull);
  }
  out_idx[row] = (float)kb;  // whole out buffer read back as f32

  const float4* p = reinterpret_cast<const float4*>(z + (size_t)row * D);
  float4 q[D / 4];
#pragma unroll
  for (int j = 0; j < D / 4; ++j) q[j] = p[j];
  float ss = 0.f;
#pragma unroll
  for (int j = 0; j < D / 4; ++j)
    ss = fmaf(q[j].x, q[j].x, fmaf(q[j].y, q[j].y, fmaf(q[j].z, q[j].z, fmaf(q[j].w, q[j].w, ss))));
  float n = fmaxf(sqrtf(ss), EPS);

  const float4* ep = reinterpret_cast<const float4*>(en + (size_t)kb * D);
  float4* op = reinterpret_cast<float4*>(out_z + (size_t)row * D);
  float s = 0.f;
#pragma unroll
  for (int j = 0; j < D / 4; ++j) {
    float4 e = ep[j];
    float4 o;
    o.x = q[j].x + (e.x - q[j].x);  // STE forward value, reference op order
    o.y = q[j].y + (e.y - q[j].y);
    o.z = q[j].z + (e.z - q[j].z);
    o.w = q[j].w + (e.w - q[j].w);
    op[j] = o;
    float dx = e.x - q[j].x / n;  float dy = e.y - q[j].y / n;
    float dz = e.z - q[j].z / n;  float dw = e.w - q[j].w / n;
    s = fmaf(dx, dx, fmaf(dy, dy, fmaf(dz, dz, fmaf(dw, dw, s))));
  }

#pragma unroll
  for (int off = 32; off > 0; off >>= 1) s += __shfl_down(s, off, 64);
  __shared__ float wsum[4];
  int lane = threadIdx.x & 63, wid = threadIdx.x >> 6;
  if (lane == 0) wsum[wid] = s;
  __syncthreads();
  if (threadIdx.x == 0) {
    float tt = (wsum[0] + wsum[1]) + (wsum[2] + wsum[3]);
    atomicAdd(loss, tt * scale);
  }
}

extern "C" void kernel_launch(void* const* d_in, const int* in_sizes, int n_in,
                              void* d_out, int out_size, void* d_ws, size_t ws_size,
                              hipStream_t stream) {
  const float* z = (const float*)d_in[0];
  const float* emb = (const float*)d_in[1];
  const int N = in_sizes[0] / D;  // 32768
  const int K = in_sizes[1] / D;  // 8192

  float* out = (float*)d_out;
  float* out_z = out;                        // N*D
  float* loss = out + (size_t)N * D;         // 1
  float* out_idx = out + (size_t)N * D + 1;  // N

  // ws layout (~2.6 MB)
  char* w = (char*)d_ws;
  float* en = (float*)w;                         w += (size_t)K * D * 4;     // 1 MB
  float* en_h = (float*)w;                       w += (size_t)K * 4;         // 32 KB
  unsigned short* eswz = (unsigned short*)w;     w += (size_t)K * D * 2 * 2; // 1 MB
  int* idx_ws = (int*)w;                         w += (size_t)N * 4;         // 128 KB
  int* list = (int*)w;                           w += (size_t)N * 4;         // 128 KB
  unsigned long long* mp2 = (unsigned long long*)w; w += (size_t)N * 8;      // 256 KB
  int* cnt = (int*)w;

  k_prep<<<dim3(K / 256), 256, 0, stream>>>(emb, en, en_h, eswz, cnt, loss);

  k_argmin_mfma<<<dim3(N / 64), 256, 0, stream>>>(
      z, eswz, idx_ws, list, cnt, mp2);

  k_cleanup<<<dim3(2048), 256, 0, stream>>>(z, en, en_h, list, cnt, mp2);

  k_epi<<<dim3(N / 256), 256, 0, stream>>>(
      z, en, idx_ws, mp2, out_z, loss, out_idx, 1.25f / (float)((size_t)N * D));
}